// Round 13
// baseline (203.242 us; speedup 1.0000x reference)
//
#include <hip/hip_runtime.h>
#include <hip/hip_bf16.h>

#define IN_F  4096
#define OUT_F 4096
#define NTOK  4096
#define RANK  32
#define GS    64
#define NG    64
#define KTOT  4160          // 4096 + 32 (low-rank) + 32 zero pad -> 65 * 64
#define NKT   65
#define ITERS 32            // tiles 0..63 in loop; tile 64 in tail
#define KCH   1024

typedef __attribute__((ext_vector_type(4)))  float f32x4;
typedef __attribute__((ext_vector_type(16))) float f32x16;
typedef __attribute__((ext_vector_type(8)))  short bf16x8;

#define AS1 __attribute__((address_space(1)))
#define AS3 __attribute__((address_space(3)))

__device__ __forceinline__ ushort f2bf(float f) {
  union { float f; uint u; } c; c.f = f;
  const uint u = c.u;
  return (ushort)((u + 0x7fffu + ((u >> 16) & 1u)) >> 16);  // RNE
}

// ---------------------------------------------------------------------------
// Kernel 1 (fused prep): blocks [0,16384) = quant, [16384,24576) = wdeq,
// [24576,24592) = aux (pu^T + zero pad + pdT transpose).
// ---------------------------------------------------------------------------
__global__ __launch_bounds__(256)
void prep_kernel(const float* __restrict__ x, const int* __restrict__ qw,
                 const float* __restrict__ wsc, const float* __restrict__ pd,
                 const float* __restrict__ pu, ushort* __restrict__ Aext,
                 ushort* __restrict__ Bext, ushort* __restrict__ pdT)
{
  const int bid = blockIdx.x;
  if (bid < 16384) {
    const int tid  = threadIdx.x;
    const int wave = tid >> 6, lane = tid & 63;
    const int sub  = lane & 15;
    const int ggrp = bid * 16 + wave * 4 + (lane >> 4);
    const int row  = ggrp >> 6, g = ggrp & 63;

    const float4 v = *(const float4*)(x + (size_t)row * IN_F + g * GS + sub * 4);
    float m = fmaxf(fmaxf(fabsf(v.x), fabsf(v.y)), fmaxf(fabsf(v.z), fabsf(v.w)));
    m = fmaxf(m, __shfl_xor(m, 1));
    m = fmaxf(m, __shfl_xor(m, 2));
    m = fmaxf(m, __shfl_xor(m, 4));
    m = fmaxf(m, __shfl_xor(m, 8));
    const float ascale = (m > 0.f) ? m * (1.f / 127.f) : 1.f;

    const float d0 = fminf(fmaxf(rintf(v.x / ascale), -127.f), 127.f) * ascale;
    const float d1 = fminf(fmaxf(rintf(v.y / ascale), -127.f), 127.f) * ascale;
    const float d2 = fminf(fmaxf(rintf(v.z / ascale), -127.f), 127.f) * ascale;
    const float d3 = fminf(fmaxf(rintf(v.w / ascale), -127.f), 127.f) * ascale;

    uint2 st;
    st.x = (uint)f2bf(d0) | ((uint)f2bf(d1) << 16);
    st.y = (uint)f2bf(d2) | ((uint)f2bf(d3) << 16);
    *(uint2*)(Aext + (size_t)row * KTOT + g * GS + sub * 4) = st;
  } else if (bid < 24576) {
    const int gidx = (bid - 16384) * 256 + threadIdx.x;
    const int o  = gidx >> 9;
    const int i0 = (gidx & 511) << 3;
    const float sc = wsc[o * NG + (i0 >> 6)];
    const int4 qa = *(const int4*)(qw + (size_t)o * IN_F + i0);
    const int4 qb = *(const int4*)(qw + (size_t)o * IN_F + i0 + 4);
    uint4 st;
    st.x = (uint)f2bf(qa.x * sc) | ((uint)f2bf(qa.y * sc) << 16);
    st.y = (uint)f2bf(qa.z * sc) | ((uint)f2bf(qa.w * sc) << 16);
    st.z = (uint)f2bf(qb.x * sc) | ((uint)f2bf(qb.y * sc) << 16);
    st.w = (uint)f2bf(qb.z * sc) | ((uint)f2bf(qb.w * sc) << 16);
    *(uint4*)(Bext + (size_t)o * KTOT + i0) = st;
  } else {
    const int id = (bid - 24576) * 256 + threadIdx.x;
    ushort* dst = Bext + (size_t)id * KTOT + IN_F;
    #pragma unroll
    for (int r = 0; r < RANK; ++r) {
      dst[r]        = f2bf(pu[(size_t)r * OUT_F + id]);
      dst[RANK + r] = 0;
    }
    #pragma unroll
    for (int r = 0; r < RANK; ++r)
      pdT[(size_t)r * IN_F + id] = f2bf(pd[(size_t)id * RANK + r]);
  }
}

// ---------------------------------------------------------------------------
// Kernel 2: lr partials = Aq @ pdT^T via MFMA (64 M-tiles x 4 K-chunks).
// ---------------------------------------------------------------------------
__global__ __launch_bounds__(256)
void lr_kernel(const ushort* __restrict__ A, const ushort* __restrict__ pdT,
               float* __restrict__ part)
{
  __shared__ alignas(16) ushort lA[64 * 64];
  const int tid  = threadIdx.x;
  const int wave = tid >> 6, lane = tid & 63;
  const int mt = blockIdx.x >> 2;
  const int kc = blockIdx.x & 3;
  const int k0 = kc * KCH;

  const int tr  = tid >> 3;
  const int scc = (tid & 7) ^ (tr & 7);
  const ushort* aSrc = A + (size_t)(mt * 64 + tr) * KTOT + k0 + scc * 8;
  char* ldsA = (char*)lA + wave * 1024;

  f32x4 acc[2];
  #pragma unroll
  for (int n = 0; n < 2; ++n) acc[n] = f32x4{0.f, 0.f, 0.f, 0.f};

  for (int kt = 0; kt < KCH / 64; ++kt) {
    const ushort* aS = aSrc + kt * 64;
    #pragma unroll
    for (int j = 0; j < 2; ++j)
      __builtin_amdgcn_global_load_lds(
          (const AS1 void*)(aS + (size_t)j * 32 * KTOT),
          (AS3 void*)(ldsA + j * 4096), 16, 0, 0);
    __syncthreads();
    #pragma unroll
    for (int ks = 0; ks < 2; ++ks) {
      const int kb  = (ks * 32 + (lane >> 4) * 8) * 2;
      const int row = wave * 16 + (lane & 15);
      const int addr = (row * 128 + kb) ^ ((row & 7) << 4);
      bf16x8 af = *(const bf16x8*)((const char*)lA + addr);
      #pragma unroll
      for (int n = 0; n < 2; ++n) {
        const int prow = n * 16 + (lane & 15);
        bf16x8 bf = *(const bf16x8*)(pdT + (size_t)prow * IN_F + k0 + kt * 64 + ks * 32 + (lane >> 4) * 8);
        acc[n] = __builtin_amdgcn_mfma_f32_16x16x32_bf16(af, bf, acc[n], 0, 0, 0);
      }
    }
    __syncthreads();
  }
  const int r0   = lane & 15;
  const int rowb = mt * 64 + wave * 16 + (lane >> 4) * 4;
  #pragma unroll
  for (int n = 0; n < 2; ++n)
    #pragma unroll
    for (int i = 0; i < 4; ++i)
      part[((size_t)kc * 4096 + rowb + i) * 32 + n * 16 + r0] = acc[n][i];
}

// ---------------------------------------------------------------------------
// Kernel 3: combine lr partials -> A_ext[:, 4096:4128], zero 4128:4160.
// ---------------------------------------------------------------------------
__global__ __launch_bounds__(256)
void lrcomb_kernel(const float* __restrict__ part, ushort* __restrict__ Aext)
{
  const int id  = blockIdx.x * 256 + threadIdx.x;
  const int row = id >> 5, r = id & 31;
  const float s = part[(size_t)row * 32 + r]
                + part[(size_t)(4096 + row) * 32 + r]
                + part[(size_t)(8192 + row) * 32 + r]
                + part[(size_t)(12288 + row) * 32 + r];
  ushort* dst = Aext + (size_t)row * KTOT + IN_F;
  dst[r]        = f2bf(s);
  dst[RANK + r] = 0;
}

// ---------------------------------------------------------------------------
// Kernel 4: 256x256 GEMM. R13 = R10 merged-phase schedule + 32x32x16 MFMA
// (2382 vs 2075 TF pipe, half the MFMA instructions, identical LDS traffic)
// + KTOT=4160 (65 tiles: 32 loop iters + tail on buf0).
// Frag maps: A/B row|col = lane&31, k = (lane>>5)*8 + j (per verified 16x16
// pattern scaled); C/D col = lane&31, row = (reg&3)+8*(reg>>2)+4*(lane>>5)
// [m74/m101]. k-slice offsets (s*32) live inside the XOR-swizzle bits ->
// 4 pre-XORed base VGPRs per operand; immediates are >=4096-aligned.
// Stage schedule, drains, barriers, LDS layout identical to R10.
// ---------------------------------------------------------------------------
#define READ_A(DST, B_, MQ_)                                                     \
  { _Pragma("unroll")                                                            \
    for (int s = 0; s < 4; ++s) {                                                \
      DST[0][s] = *(const bf16x8*)(lds + aB[s] + ((B_) * 32768 + (MQ_) * 8192)); \
      DST[1][s] = *(const bf16x8*)(lds + aB[s] + ((B_) * 32768 + (MQ_) * 8192 + 4096)); \
    } }

#define READ_B(DST, B_, N_)                                                      \
  { _Pragma("unroll")                                                            \
    for (int s = 0; s < 4; ++s)                                                  \
      DST[s] = *(const bf16x8*)(lds + bB[s] + ((B_) * 32768 + (N_) * 4096)); }

#define MFMA32(MQ_, AF, B0_, B1_)                                                \
  _Pragma("unroll")                                                              \
  for (int s = 0; s < 4; ++s)                                                    \
    _Pragma("unroll")                                                            \
    for (int m2 = 0; m2 < 2; ++m2) {                                             \
      acc[(MQ_) * 2 + m2][0] = __builtin_amdgcn_mfma_f32_32x32x16_bf16(          \
          AF[m2][s], B0_[s], acc[(MQ_) * 2 + m2][0], 0, 0, 0);                   \
      acc[(MQ_) * 2 + m2][1] = __builtin_amdgcn_mfma_f32_32x32x16_bf16(          \
          AF[m2][s], B1_[s], acc[(MQ_) * 2 + m2][1], 0, 0, 0);                   \
    }

#define STAGE_A(B_, S0, S1, D0, D1, T_)                                          \
  { const ushort* s0 = Atile + S0 + (T_) * 64;                                   \
    const ushort* s1 = Atile + S1 + (T_) * 64;                                   \
    __builtin_amdgcn_global_load_lds((const AS1 void*)s0,                        \
        (AS3 void*)(lds + (B_) * 32768 + D0), 16, 0, 0);                         \
    __builtin_amdgcn_global_load_lds((const AS1 void*)s1,                        \
        (AS3 void*)(lds + (B_) * 32768 + D1), 16, 0, 0); }

#define STAGE_B(B_, S0, S1, D0, D1, T_)                                          \
  { const ushort* s0 = Btile + S0 + (T_) * 64;                                   \
    const ushort* s1 = Btile + S1 + (T_) * 64;                                   \
    __builtin_amdgcn_global_load_lds((const AS1 void*)s0,                        \
        (AS3 void*)(lds + 65536 + (B_) * 32768 + D0), 16, 0, 0);                 \
    __builtin_amdgcn_global_load_lds((const AS1 void*)s1,                        \
        (AS3 void*)(lds + 65536 + (B_) * 32768 + D1), 16, 0, 0); }

#define BAR __builtin_amdgcn_s_barrier()
#define DRAIN4 asm volatile("s_waitcnt vmcnt(4)" ::: "memory")
#define PRIO1 __builtin_amdgcn_s_setprio(1)
#define PRIO0 __builtin_amdgcn_s_setprio(0)

__global__ __launch_bounds__(512, 2)
void gemm256_kernel(const ushort* __restrict__ A, const ushort* __restrict__ B,
                    const float* __restrict__ bias, float* __restrict__ C)
{
  extern __shared__ char lds[];
  const int tid = threadIdx.x;
  const int w = tid >> 6, lane = tid & 63;
  const int wm = w >> 2, wn = w & 3;          // 2 x 4 waves
  const int L = lane & 31;                    // row/col within 32-tile
  const int g16 = (lane >> 5) * 16;           // k-group byte offset

  // 4 pre-XORed ds_read bases per operand (k-slice s inside swizzle bits).
  int aB[4], bB[4];
  #pragma unroll
  for (int s = 0; s < 4; ++s) {
    const int pre = L * 128 + s * 32 + g16;
    const int sw  = pre ^ ((L & 7) << 4);
    aB[s] = wm * 16384 + sw;
    bB[s] = 65536 + wn * 8192 + sw;
  }

  // Stage source offsets (ushort units) and LDS dest offsets (bytes).
  const int coff = ((lane & 7) ^ (lane >> 3)) << 3;
  const int g0 = w * 2, g1 = w * 2 + 1;
  const int aq0 = (g0 >> 3) * 2, asub0 = g0 & 7;
  const int aq1 = (g1 >> 3) * 2, asub1 = g1 & 7;
  const int aS00 = (aq0 * 64 + asub0 * 8 + (lane >> 3)) * KTOT + coff;
  const int aS01 = (aq1 * 64 + asub1 * 8 + (lane >> 3)) * KTOT + coff;
  const int aS10 = ((aq0 + 1) * 64 + asub0 * 8 + (lane >> 3)) * KTOT + coff;
  const int aS11 = ((aq1 + 1) * 64 + asub1 * 8 + (lane >> 3)) * KTOT + coff;
  const int aD00 = aq0 * 8192 + asub0 * 1024;
  const int aD01 = aq1 * 8192 + asub1 * 1024;
  const int aD10 = (aq0 + 1) * 8192 + asub0 * 1024;
  const int aD11 = (aq1 + 1) * 8192 + asub1 * 1024;
  const int bj0 = g0 >> 2, bsub0 = g0 & 3;
  const int bj1 = g1 >> 2, bsub1 = g1 & 3;
  const int bS00 = (bj0 * 64 + bsub0 * 8 + (lane >> 3)) * KTOT + coff;
  const int bS01 = (bj1 * 64 + bsub1 * 8 + (lane >> 3)) * KTOT + coff;
  const int bS10 = (bj0 * 64 + 32 + bsub0 * 8 + (lane >> 3)) * KTOT + coff;
  const int bS11 = (bj1 * 64 + 32 + bsub1 * 8 + (lane >> 3)) * KTOT + coff;
  const int bD00 = bj0 * 8192 + bsub0 * 1024;
  const int bD01 = bj1 * 8192 + bsub1 * 1024;
  const int bD10 = bj0 * 8192 + 4096 + bsub0 * 1024;
  const int bD11 = bj1 * 8192 + 4096 + bsub1 * 1024;

  // 2-D XCD chunk swizzle: each XCD owns a 4x8 (bm x bn) region.
  const int xcd = blockIdx.x & 7, idx = blockIdx.x >> 3;
  const int bm = (xcd >> 1) * 4 + (idx >> 3);
  const int bn = (xcd & 1) * 8 + (idx & 7);

  const ushort* Atile = A + (size_t)bm * 256 * KTOT;
  const ushort* Btile = B + (size_t)bn * 256 * KTOT;

  f32x16 acc[4][2];
  #pragma unroll
  for (int m = 0; m < 4; ++m)
    #pragma unroll
    for (int n = 0; n < 2; ++n)
      #pragma unroll
      for (int r = 0; r < 16; ++r)
        acc[m][n][r] = 0.f;

  bf16x8 afA[2][4], af2[2][4], b0[4], b1[4];

  // Prologue: buf0 <- tile 0 full (8 loads); buf1 <- tile 1 h0 (4 loads).
  STAGE_A(0, aS00, aS01, aD00, aD01, 0);
  STAGE_B(0, bS00, bS01, bD00, bD01, 0);
  STAGE_A(0, aS10, aS11, aD10, aD11, 0);
  STAGE_B(0, bS10, bS11, bD10, bD11, 0);
  STAGE_A(1, aS00, aS01, aD00, aD01, 1);
  STAGE_B(1, bS00, bS01, bD00, bD01, 1);
  DRAIN4;           // buf0 complete; buf1-h0's 4 loads outstanding
  BAR;

  #pragma unroll 1
  for (int j = 0; j < ITERS; ++j) {
    const int t1 = 2 * j + 1;
    const int t2 = (2 * j + 2 < NKT) ? 2 * j + 2 : NKT - 1;   // clamped
    const int t3 = (2 * j + 3 < NKT) ? 2 * j + 3 : NKT - 1;   // (dup of 64, unread)

    // M1 (buf0, MQ0): reads afA+b0+b1; stage (1,h1,t1); MFMA.
    READ_A(afA, 0, 0);
    READ_B(b0, 0, 0);
    READ_B(b1, 0, 1);
    STAGE_A(1, aS10, aS11, aD10, aD11, t1);
    STAGE_B(1, bS10, bS11, bD10, bD11, t1);
    BAR;
    PRIO1; MFMA32(0, afA, b0, b1); PRIO0;
    BAR;
    // M2 (buf0, MQ1): reads af2; stage (0,h0,t2); MFMA; drain.
    READ_A(af2, 0, 1);
    STAGE_A(0, aS00, aS01, aD00, aD01, t2);
    STAGE_B(0, bS00, bS01, bD00, bD01, t2);
    BAR;
    PRIO1; MFMA32(1, af2, b0, b1); PRIO0;
    DRAIN4;
    BAR;
    // M3 (buf1, MQ0): reads afA+b0+b1; stage (0,h1,t2); MFMA.
    READ_A(afA, 1, 0);
    READ_B(b0, 1, 0);
    READ_B(b1, 1, 1);
    STAGE_A(0, aS10, aS11, aD10, aD11, t2);
    STAGE_B(0, bS10, bS11, bD10, bD11, t2);
    BAR;
    PRIO1; MFMA32(0, afA, b0, b1); PRIO0;
    BAR;
    // M4 (buf1, MQ1): reads af2; stage (1,h0,t3); MFMA; drain.
    READ_A(af2, 1, 1);
    STAGE_A(1, aS00, aS01, aD00, aD01, t3);
    STAGE_B(1, bS00, bS01, bD00, bD01, t3);
    BAR;
    PRIO1; MFMA32(1, af2, b0, b1); PRIO0;
    DRAIN4;
    BAR;
  }

  // Tail: tile 64 resides fully in buf0 (staged M2/M3 of j=31; drained M4).
  READ_A(afA, 0, 0);
  READ_B(b0, 0, 0);
  READ_B(b1, 0, 1);
  MFMA32(0, afA, b0, b1);
  READ_A(af2, 0, 1);
  MFMA32(1, af2, b0, b1);

  // Epilogue: C = acc + bias. 32x32 C/D map: col = lane&31,
  // row = (reg&3) + 8*(reg>>2) + 4*(lane>>5)  [m74/m101 verified].
  const int rofs = 4 * (lane >> 5);
  #pragma unroll
  for (int n = 0; n < 2; ++n) {
    const int col = bn * 256 + wn * 64 + n * 32 + L;
    const float bv = bias[col];
    #pragma unroll
    for (int m = 0; m < 4; ++m) {
      const int rowb = bm * 256 + wm * 128 + m * 32 + rofs;
      #pragma unroll
      for (int r = 0; r < 16; ++r) {
        const int row = rowb + (r & 3) + 8 * (r >> 2);
        C[(size_t)row * OUT_F + col] = acc[m][n][r] + bv;
      }
    }
  }
}

// ---------------------------------------------------------------------------
extern "C" void kernel_launch(void* const* d_in, const int* in_sizes, int n_in,
                              void* d_out, int out_size, void* d_ws, size_t ws_size,
                              hipStream_t stream) {
  const float* x    = (const float*)d_in[0];
  const int*   qw   = (const int*)d_in[1];
  const float* wsc  = (const float*)d_in[2];
  const float* bias = (const float*)d_in[3];
  const float* pd   = (const float*)d_in[4];
  const float* pu   = (const float*)d_in[5];
  float* out = (float*)d_out;

  ushort* Aext = (ushort*)d_ws;                        // [4096][4160] bf16
  ushort* Bext = Aext + (size_t)NTOK * KTOT;           // [4096][4160] bf16
  ushort* pdT  = Bext + (size_t)OUT_F * KTOT;          // [32][4096] bf16
  float*  part = (float*)(pdT + (size_t)RANK * IN_F);  // [4][4096][32] f32

  hipFuncSetAttribute(reinterpret_cast<const void*>(gemm256_kernel),
                      hipFuncAttributeMaxDynamicSharedMemorySize, 131072);

  prep_kernel  <<<24592, 256, 0, stream>>>(x, qw, wsc, pd, pu, Aext, Bext, pdT);
  lr_kernel    <<<  256, 256, 0, stream>>>(Aext, pdT, part);
  lrcomb_kernel<<<  512, 256, 0, stream>>>(part, Aext);
  gemm256_kernel<<< 256, 512, 131072, stream>>>(Aext, Bext, bias, out);
}

// Round 14
// 171.312 us; speedup vs baseline: 1.1864x; 1.1864x over previous
//
#include <hip/hip_runtime.h>
#include <hip/hip_bf16.h>

#define IN_F  4096
#define OUT_F 4096
#define NTOK  4096
#define RANK  32
#define GS    64
#define NG    64
#define KTOT  4160          // 4096 + 32 (low-rank) + 32 zero pad -> 65 * 64
#define NKT   65
#define ITERS 32            // tiles 0..63 in loop; tile 64 in buf0 tail
#define KCH   1024

typedef __attribute__((ext_vector_type(4))) float f32x4;
typedef __attribute__((ext_vector_type(8))) short bf16x8;

#define AS1 __attribute__((address_space(1)))
#define AS3 __attribute__((address_space(3)))

__device__ __forceinline__ ushort f2bf(float f) {
  union { float f; uint u; } c; c.f = f;
  const uint u = c.u;
  return (ushort)((u + 0x7fffu + ((u >> 16) & 1u)) >> 16);  // RNE
}

// ---------------------------------------------------------------------------
// Kernel 1 (fused prep): blocks [0,16384) = quant, [16384,24576) = wdeq,
// [24576,24592) = aux (pu^T + zero pad + pdT transpose).
// ---------------------------------------------------------------------------
__global__ __launch_bounds__(256)
void prep_kernel(const float* __restrict__ x, const int* __restrict__ qw,
                 const float* __restrict__ wsc, const float* __restrict__ pd,
                 const float* __restrict__ pu, ushort* __restrict__ Aext,
                 ushort* __restrict__ Bext, ushort* __restrict__ pdT)
{
  const int bid = blockIdx.x;
  if (bid < 16384) {
    const int tid  = threadIdx.x;
    const int wave = tid >> 6, lane = tid & 63;
    const int sub  = lane & 15;
    const int ggrp = bid * 16 + wave * 4 + (lane >> 4);
    const int row  = ggrp >> 6, g = ggrp & 63;

    const float4 v = *(const float4*)(x + (size_t)row * IN_F + g * GS + sub * 4);
    float m = fmaxf(fmaxf(fabsf(v.x), fabsf(v.y)), fmaxf(fabsf(v.z), fabsf(v.w)));
    m = fmaxf(m, __shfl_xor(m, 1));
    m = fmaxf(m, __shfl_xor(m, 2));
    m = fmaxf(m, __shfl_xor(m, 4));
    m = fmaxf(m, __shfl_xor(m, 8));
    const float ascale = (m > 0.f) ? m * (1.f / 127.f) : 1.f;

    const float d0 = fminf(fmaxf(rintf(v.x / ascale), -127.f), 127.f) * ascale;
    const float d1 = fminf(fmaxf(rintf(v.y / ascale), -127.f), 127.f) * ascale;
    const float d2 = fminf(fmaxf(rintf(v.z / ascale), -127.f), 127.f) * ascale;
    const float d3 = fminf(fmaxf(rintf(v.w / ascale), -127.f), 127.f) * ascale;

    uint2 st;
    st.x = (uint)f2bf(d0) | ((uint)f2bf(d1) << 16);
    st.y = (uint)f2bf(d2) | ((uint)f2bf(d3) << 16);
    *(uint2*)(Aext + (size_t)row * KTOT + g * GS + sub * 4) = st;
  } else if (bid < 24576) {
    const int gidx = (bid - 16384) * 256 + threadIdx.x;
    const int o  = gidx >> 9;
    const int i0 = (gidx & 511) << 3;
    const float sc = wsc[o * NG + (i0 >> 6)];
    const int4 qa = *(const int4*)(qw + (size_t)o * IN_F + i0);
    const int4 qb = *(const int4*)(qw + (size_t)o * IN_F + i0 + 4);
    uint4 st;
    st.x = (uint)f2bf(qa.x * sc) | ((uint)f2bf(qa.y * sc) << 16);
    st.y = (uint)f2bf(qa.z * sc) | ((uint)f2bf(qa.w * sc) << 16);
    st.z = (uint)f2bf(qb.x * sc) | ((uint)f2bf(qb.y * sc) << 16);
    st.w = (uint)f2bf(qb.z * sc) | ((uint)f2bf(qb.w * sc) << 16);
    *(uint4*)(Bext + (size_t)o * KTOT + i0) = st;
  } else {
    const int id = (bid - 24576) * 256 + threadIdx.x;
    ushort* dst = Bext + (size_t)id * KTOT + IN_F;
    #pragma unroll
    for (int r = 0; r < RANK; ++r) {
      dst[r]        = f2bf(pu[(size_t)r * OUT_F + id]);
      dst[RANK + r] = 0;
    }
    #pragma unroll
    for (int r = 0; r < RANK; ++r)
      pdT[(size_t)r * IN_F + id] = f2bf(pd[(size_t)id * RANK + r]);
  }
}

// ---------------------------------------------------------------------------
// Kernel 2: lr partials = Aq @ pdT^T via MFMA (64 M-tiles x 4 K-chunks).
// ---------------------------------------------------------------------------
__global__ __launch_bounds__(256)
void lr_kernel(const ushort* __restrict__ A, const ushort* __restrict__ pdT,
               float* __restrict__ part)
{
  __shared__ alignas(16) ushort lA[64 * 64];
  const int tid  = threadIdx.x;
  const int wave = tid >> 6, lane = tid & 63;
  const int mt = blockIdx.x >> 2;
  const int kc = blockIdx.x & 3;
  const int k0 = kc * KCH;

  const int tr  = tid >> 3;
  const int scc = (tid & 7) ^ (tr & 7);
  const ushort* aSrc = A + (size_t)(mt * 64 + tr) * KTOT + k0 + scc * 8;
  char* ldsA = (char*)lA + wave * 1024;

  f32x4 acc[2];
  #pragma unroll
  for (int n = 0; n < 2; ++n) acc[n] = f32x4{0.f, 0.f, 0.f, 0.f};

  for (int kt = 0; kt < KCH / 64; ++kt) {
    const ushort* aS = aSrc + kt * 64;
    #pragma unroll
    for (int j = 0; j < 2; ++j)
      __builtin_amdgcn_global_load_lds(
          (const AS1 void*)(aS + (size_t)j * 32 * KTOT),
          (AS3 void*)(ldsA + j * 4096), 16, 0, 0);
    __syncthreads();
    #pragma unroll
    for (int ks = 0; ks < 2; ++ks) {
      const int kb  = (ks * 32 + (lane >> 4) * 8) * 2;
      const int row = wave * 16 + (lane & 15);
      const int addr = (row * 128 + kb) ^ ((row & 7) << 4);
      bf16x8 af = *(const bf16x8*)((const char*)lA + addr);
      #pragma unroll
      for (int n = 0; n < 2; ++n) {
        const int prow = n * 16 + (lane & 15);
        bf16x8 bf = *(const bf16x8*)(pdT + (size_t)prow * IN_F + k0 + kt * 64 + ks * 32 + (lane >> 4) * 8);
        acc[n] = __builtin_amdgcn_mfma_f32_16x16x32_bf16(af, bf, acc[n], 0, 0, 0);
      }
    }
    __syncthreads();
  }
  const int r0   = lane & 15;
  const int rowb = mt * 64 + wave * 16 + (lane >> 4) * 4;
  #pragma unroll
  for (int n = 0; n < 2; ++n)
    #pragma unroll
    for (int i = 0; i < 4; ++i)
      part[((size_t)kc * 4096 + rowb + i) * 32 + n * 16 + r0] = acc[n][i];
}

// ---------------------------------------------------------------------------
// Kernel 3: combine lr partials -> A_ext[:, 4096:4128], zero 4128:4160.
// ---------------------------------------------------------------------------
__global__ __launch_bounds__(256)
void lrcomb_kernel(const float* __restrict__ part, ushort* __restrict__ Aext)
{
  const int id  = blockIdx.x * 256 + threadIdx.x;
  const int row = id >> 5, r = id & 31;
  const float s = part[(size_t)row * 32 + r]
                + part[(size_t)(4096 + row) * 32 + r]
                + part[(size_t)(8192 + row) * 32 + r]
                + part[(size_t)(12288 + row) * 32 + r];
  ushort* dst = Aext + (size_t)row * KTOT + IN_F;
  dst[r]        = f2bf(s);
  dst[RANK + r] = 0;
}

// ---------------------------------------------------------------------------
// Kernel 4: 256x256 GEMM. R14 = R10 merged-phase schedule (proven: 0
// conflicts, best 128.4 us) with KTOT=4160: 32 loop iters (tiles 0..63) +
// tail on buf0 (tile 64, staged by j=31 M2/M3; clamped t3 dup-stages touch
// only unread buf1 quarters). Everything else identical to R10.
// ---------------------------------------------------------------------------
#define READ_AF8(DST, B_, MQ_)                                                   \
  { _Pragma("unroll")                                                            \
    for (int mf = 0; mf < 4; ++mf) {                                             \
      DST[mf][0] = *(const bf16x8*)(lds + afB0 + ((B_) * 32768 + (MQ_) * 8192 + mf * 2048)); \
      DST[mf][1] = *(const bf16x8*)(lds + afB1 + ((B_) * 32768 + (MQ_) * 8192 + mf * 2048)); \
    } }

#define READ_BF4(DST, B_, NQ_)                                                   \
  { _Pragma("unroll")                                                            \
    for (int nf = 0; nf < 2; ++nf) {                                             \
      DST[nf][0] = *(const bf16x8*)(lds + bfB0 + ((B_) * 32768 + (NQ_) * 4096 + nf * 2048)); \
      DST[nf][1] = *(const bf16x8*)(lds + bfB1 + ((B_) * 32768 + (NQ_) * 4096 + nf * 2048)); \
    } }

#define MFMA16(MQ_, NQ_, AF, BF)                                                 \
  _Pragma("unroll")                                                              \
  for (int mf = 0; mf < 4; ++mf)                                                 \
    _Pragma("unroll")                                                            \
    for (int nf = 0; nf < 2; ++nf)                                               \
      _Pragma("unroll")                                                          \
      for (int ks = 0; ks < 2; ++ks)                                             \
        acc[(MQ_) * 4 + mf][(NQ_) * 2 + nf] =                                    \
            __builtin_amdgcn_mfma_f32_16x16x32_bf16(AF[mf][ks], BF[nf][ks],      \
                acc[(MQ_) * 4 + mf][(NQ_) * 2 + nf], 0, 0, 0);

#define STAGE_A(B_, S0, S1, D0, D1, T_)                                          \
  { const ushort* s0 = Atile + S0 + (T_) * 64;                                   \
    const ushort* s1 = Atile + S1 + (T_) * 64;                                   \
    __builtin_amdgcn_global_load_lds((const AS1 void*)s0,                        \
        (AS3 void*)(lds + (B_) * 32768 + D0), 16, 0, 0);                         \
    __builtin_amdgcn_global_load_lds((const AS1 void*)s1,                        \
        (AS3 void*)(lds + (B_) * 32768 + D1), 16, 0, 0); }

#define STAGE_B(B_, S0, S1, D0, D1, T_)                                          \
  { const ushort* s0 = Btile + S0 + (T_) * 64;                                   \
    const ushort* s1 = Btile + S1 + (T_) * 64;                                   \
    __builtin_amdgcn_global_load_lds((const AS1 void*)s0,                        \
        (AS3 void*)(lds + 65536 + (B_) * 32768 + D0), 16, 0, 0);                 \
    __builtin_amdgcn_global_load_lds((const AS1 void*)s1,                        \
        (AS3 void*)(lds + 65536 + (B_) * 32768 + D1), 16, 0, 0); }

#define BAR __builtin_amdgcn_s_barrier()
#define DRAIN4 asm volatile("s_waitcnt vmcnt(4)" ::: "memory")
#define PRIO1 __builtin_amdgcn_s_setprio(1)
#define PRIO0 __builtin_amdgcn_s_setprio(0)

__global__ __launch_bounds__(512, 2)
void gemm256_kernel(const ushort* __restrict__ A, const ushort* __restrict__ B,
                    const float* __restrict__ bias, float* __restrict__ C)
{
  extern __shared__ char lds[];
  const int tid = threadIdx.x;
  const int w = tid >> 6, lane = tid & 63;
  const int l15 = lane & 15;
  const int wm = w >> 2, wn = w & 3;          // 2 x 4 waves

  // ds_read base vaddrs; imm offsets carry B_/MQ_/NQ_/frag (fit 16-bit).
  const int swz0 = (l15 * 128 + (lane >> 4) * 16) ^ ((l15 & 7) << 4);
  const int swz1 = (l15 * 128 + 64 + (lane >> 4) * 16) ^ ((l15 & 7) << 4);
  const int afB0 = wm * 16384 + swz0;
  const int afB1 = wm * 16384 + swz1;
  const int bfB0 = 65536 + wn * 8192 + swz0;
  const int bfB1 = 65536 + wn * 8192 + swz1;

  // Stage source offsets (ushort units) and LDS dest offsets (bytes).
  const int coff = ((lane & 7) ^ (lane >> 3)) << 3;
  const int g0 = w * 2, g1 = w * 2 + 1;
  const int aq0 = (g0 >> 3) * 2, asub0 = g0 & 7;
  const int aq1 = (g1 >> 3) * 2, asub1 = g1 & 7;
  const int aS00 = (aq0 * 64 + asub0 * 8 + (lane >> 3)) * KTOT + coff;
  const int aS01 = (aq1 * 64 + asub1 * 8 + (lane >> 3)) * KTOT + coff;
  const int aS10 = ((aq0 + 1) * 64 + asub0 * 8 + (lane >> 3)) * KTOT + coff;
  const int aS11 = ((aq1 + 1) * 64 + asub1 * 8 + (lane >> 3)) * KTOT + coff;
  const int aD00 = aq0 * 8192 + asub0 * 1024;
  const int aD01 = aq1 * 8192 + asub1 * 1024;
  const int aD10 = (aq0 + 1) * 8192 + asub0 * 1024;
  const int aD11 = (aq1 + 1) * 8192 + asub1 * 1024;
  const int bj0 = g0 >> 2, bsub0 = g0 & 3;
  const int bj1 = g1 >> 2, bsub1 = g1 & 3;
  const int bS00 = (bj0 * 64 + bsub0 * 8 + (lane >> 3)) * KTOT + coff;
  const int bS01 = (bj1 * 64 + bsub1 * 8 + (lane >> 3)) * KTOT + coff;
  const int bS10 = (bj0 * 64 + 32 + bsub0 * 8 + (lane >> 3)) * KTOT + coff;
  const int bS11 = (bj1 * 64 + 32 + bsub1 * 8 + (lane >> 3)) * KTOT + coff;
  const int bD00 = bj0 * 8192 + bsub0 * 1024;
  const int bD01 = bj1 * 8192 + bsub1 * 1024;
  const int bD10 = bj0 * 8192 + 4096 + bsub0 * 1024;
  const int bD11 = bj1 * 8192 + 4096 + bsub1 * 1024;

  // 2-D XCD chunk swizzle: each XCD owns a 4x8 (bm x bn) region.
  const int xcd = blockIdx.x & 7, idx = blockIdx.x >> 3;
  const int bm = (xcd >> 1) * 4 + (idx >> 3);
  const int bn = (xcd & 1) * 8 + (idx & 7);

  const ushort* Atile = A + (size_t)bm * 256 * KTOT;
  const ushort* Btile = B + (size_t)bn * 256 * KTOT;

  f32x4 acc[8][4];
  #pragma unroll
  for (int m = 0; m < 8; ++m)
    #pragma unroll
    for (int n = 0; n < 4; ++n)
      acc[m][n] = f32x4{0.f, 0.f, 0.f, 0.f};

  bf16x8 afA[4][2], af2[4][2], b0[2][2], b1[2][2];

  // Prologue: buf0 <- tile 0 full (8 loads); buf1 <- tile 1 h0 (4 loads).
  STAGE_A(0, aS00, aS01, aD00, aD01, 0);
  STAGE_B(0, bS00, bS01, bD00, bD01, 0);
  STAGE_A(0, aS10, aS11, aD10, aD11, 0);
  STAGE_B(0, bS10, bS11, bD10, bD11, 0);
  STAGE_A(1, aS00, aS01, aD00, aD01, 1);
  STAGE_B(1, bS00, bS01, bD00, bD01, 1);
  DRAIN4;           // buf0 complete; buf1-h0's 4 loads outstanding
  BAR;

  #pragma unroll 1
  for (int j = 0; j < ITERS; ++j) {
    const int t1 = 2 * j + 1;
    const int t2 = 2 * j + 2;                                  // <= 64 ✓
    const int t3 = (2 * j + 3 < NKT) ? 2 * j + 3 : NKT - 1;    // clamp (dup, unread)

    // M1: reads buf0 {afA(MQ0), b0, b1}; stage A(1,h1,t1)+B(1,h1,t1);
    //     MFMA (0,0)+(0,1) buf0.
    READ_AF8(afA, 0, 0);
    READ_BF4(b0, 0, 0);
    READ_BF4(b1, 0, 1);
    STAGE_A(1, aS10, aS11, aD10, aD11, t1);
    STAGE_B(1, bS10, bS11, bD10, bD11, t1);
    BAR;
    PRIO1; MFMA16(0, 0, afA, b0); MFMA16(0, 1, afA, b1); PRIO0;
    BAR;
    // M2: reads buf0 {af2(MQ1)}; stage A(0,h0,t2)+B(0,h0,t2);
    //     MFMA (1,0)+(1,1) buf0; drain.
    READ_AF8(af2, 0, 1);
    STAGE_A(0, aS00, aS01, aD00, aD01, t2);
    STAGE_B(0, bS00, bS01, bD00, bD01, t2);
    BAR;
    PRIO1; MFMA16(1, 0, af2, b0); MFMA16(1, 1, af2, b1); PRIO0;
    DRAIN4;
    BAR;
    // M3: reads buf1 {afA(MQ0), b0, b1}; stage A(0,h1,t2)+B(0,h1,t2);
    //     MFMA (0,0)+(0,1) buf1.
    READ_AF8(afA, 1, 0);
    READ_BF4(b0, 1, 0);
    READ_BF4(b1, 1, 1);
    STAGE_A(0, aS10, aS11, aD10, aD11, t2);
    STAGE_B(0, bS10, bS11, bD10, bD11, t2);
    BAR;
    PRIO1; MFMA16(0, 0, afA, b0); MFMA16(0, 1, afA, b1); PRIO0;
    BAR;
    // M4: reads buf1 {af2(MQ1)}; stage A(1,h0,t3)+B(1,h0,t3);
    //     MFMA (1,0)+(1,1) buf1; drain.
    READ_AF8(af2, 1, 1);
    STAGE_A(1, aS00, aS01, aD00, aD01, t3);
    STAGE_B(1, bS00, bS01, bD00, bD01, t3);
    BAR;
    PRIO1; MFMA16(1, 0, af2, b0); MFMA16(1, 1, af2, b1); PRIO0;
    DRAIN4;
    BAR;
  }

  // Tail: tile 64 fully resident in buf0 (staged j=31 M2/M3; drained at M4's
  // vmcnt(4): the 4 outstanding loads are M4's dup stages into buf1 only).
  READ_AF8(afA, 0, 0);
  READ_BF4(b0, 0, 0);
  READ_BF4(b1, 0, 1);
  MFMA16(0, 0, afA, b0); MFMA16(0, 1, afA, b1);
  READ_AF8(af2, 0, 1);
  MFMA16(1, 0, af2, b0); MFMA16(1, 1, af2, b1);

  // Epilogue: C = acc + bias. acc frag: col = l15, row = (lane>>4)*4 + i.
  const int csub = lane >> 4;
  #pragma unroll
  for (int nf = 0; nf < 4; ++nf) {
    const int col = bn * 256 + wn * 64 + nf * 16 + l15;
    const float bv = bias[col];
    #pragma unroll
    for (int mf = 0; mf < 8; ++mf) {
      const int row = bm * 256 + wm * 128 + mf * 16 + csub * 4;
      #pragma unroll
      for (int i = 0; i < 4; ++i)
        C[(size_t)(row + i) * OUT_F + col] = acc[mf][nf][i] + bv;
    }
  }
}

// ---------------------------------------------------------------------------
extern "C" void kernel_launch(void* const* d_in, const int* in_sizes, int n_in,
                              void* d_out, int out_size, void* d_ws, size_t ws_size,
                              hipStream_t stream) {
  const float* x    = (const float*)d_in[0];
  const int*   qw   = (const int*)d_in[1];
  const float* wsc  = (const float*)d_in[2];
  const float* bias = (const float*)d_in[3];
  const float* pd   = (const float*)d_in[4];
  const float* pu   = (const float*)d_in[5];
  float* out = (float*)d_out;

  ushort* Aext = (ushort*)d_ws;                        // [4096][4160] bf16
  ushort* Bext = Aext + (size_t)NTOK * KTOT;           // [4096][4160] bf16
  ushort* pdT  = Bext + (size_t)OUT_F * KTOT;          // [32][4096] bf16
  float*  part = (float*)(pdT + (size_t)RANK * IN_F);  // [4][4096][32] f32

  hipFuncSetAttribute(reinterpret_cast<const void*>(gemm256_kernel),
                      hipFuncAttributeMaxDynamicSharedMemorySize, 131072);

  prep_kernel  <<<24592, 256, 0, stream>>>(x, qw, wsc, pd, pu, Aext, Bext, pdT);
  lr_kernel    <<<  256, 256, 0, stream>>>(Aext, pdT, part);
  lrcomb_kernel<<<  512, 256, 0, stream>>>(part, Aext);
  gemm256_kernel<<< 256, 512, 131072, stream>>>(Aext, Bext, bias, out);
}

// Round 15
// 170.609 us; speedup vs baseline: 1.1913x; 1.0041x over previous
//
#include <hip/hip_runtime.h>
#include <hip/hip_bf16.h>

#define IN_F  4096
#define OUT_F 4096
#define NTOK  4096
#define RANK  32
#define GS    64
#define NG    64
#define KTOT  4160          // 4096 + 32 (low-rank) + 32 zero pad -> 65 * 64
#define NKT   65
#define ITERS 32            // tiles 0..63 in loop; tile 64 in buf0 tail
#define KCH   1024

typedef __attribute__((ext_vector_type(4))) float f32x4;
typedef __attribute__((ext_vector_type(8))) short bf16x8;

#define AS1 __attribute__((address_space(1)))
#define AS3 __attribute__((address_space(3)))

__device__ __forceinline__ ushort f2bf(float f) {
  union { float f; uint u; } c; c.f = f;
  const uint u = c.u;
  return (ushort)((u + 0x7fffu + ((u >> 16) & 1u)) >> 16);  // RNE
}

// ---------------------------------------------------------------------------
// Kernel 1 (fused prep): blocks [0,16384) = quant, [16384,24576) = wdeq,
// [24576,24592) = aux (pu^T + zero pad + pdT transpose).
// ---------------------------------------------------------------------------
__global__ __launch_bounds__(256)
void prep_kernel(const float* __restrict__ x, const int* __restrict__ qw,
                 const float* __restrict__ wsc, const float* __restrict__ pd,
                 const float* __restrict__ pu, ushort* __restrict__ Aext,
                 ushort* __restrict__ Bext, ushort* __restrict__ pdT)
{
  const int bid = blockIdx.x;
  if (bid < 16384) {
    const int tid  = threadIdx.x;
    const int wave = tid >> 6, lane = tid & 63;
    const int sub  = lane & 15;
    const int ggrp = bid * 16 + wave * 4 + (lane >> 4);
    const int row  = ggrp >> 6, g = ggrp & 63;

    const float4 v = *(const float4*)(x + (size_t)row * IN_F + g * GS + sub * 4);
    float m = fmaxf(fmaxf(fabsf(v.x), fabsf(v.y)), fmaxf(fabsf(v.z), fabsf(v.w)));
    m = fmaxf(m, __shfl_xor(m, 1));
    m = fmaxf(m, __shfl_xor(m, 2));
    m = fmaxf(m, __shfl_xor(m, 4));
    m = fmaxf(m, __shfl_xor(m, 8));
    const float ascale = (m > 0.f) ? m * (1.f / 127.f) : 1.f;

    const float d0 = fminf(fmaxf(rintf(v.x / ascale), -127.f), 127.f) * ascale;
    const float d1 = fminf(fmaxf(rintf(v.y / ascale), -127.f), 127.f) * ascale;
    const float d2 = fminf(fmaxf(rintf(v.z / ascale), -127.f), 127.f) * ascale;
    const float d3 = fminf(fmaxf(rintf(v.w / ascale), -127.f), 127.f) * ascale;

    uint2 st;
    st.x = (uint)f2bf(d0) | ((uint)f2bf(d1) << 16);
    st.y = (uint)f2bf(d2) | ((uint)f2bf(d3) << 16);
    *(uint2*)(Aext + (size_t)row * KTOT + g * GS + sub * 4) = st;
  } else if (bid < 24576) {
    const int gidx = (bid - 16384) * 256 + threadIdx.x;
    const int o  = gidx >> 9;
    const int i0 = (gidx & 511) << 3;
    const float sc = wsc[o * NG + (i0 >> 6)];
    const int4 qa = *(const int4*)(qw + (size_t)o * IN_F + i0);
    const int4 qb = *(const int4*)(qw + (size_t)o * IN_F + i0 + 4);
    uint4 st;
    st.x = (uint)f2bf(qa.x * sc) | ((uint)f2bf(qa.y * sc) << 16);
    st.y = (uint)f2bf(qa.z * sc) | ((uint)f2bf(qa.w * sc) << 16);
    st.z = (uint)f2bf(qb.x * sc) | ((uint)f2bf(qb.y * sc) << 16);
    st.w = (uint)f2bf(qb.z * sc) | ((uint)f2bf(qb.w * sc) << 16);
    *(uint4*)(Bext + (size_t)o * KTOT + i0) = st;
  } else {
    const int id = (bid - 24576) * 256 + threadIdx.x;
    ushort* dst = Bext + (size_t)id * KTOT + IN_F;
    #pragma unroll
    for (int r = 0; r < RANK; ++r) {
      dst[r]        = f2bf(pu[(size_t)r * OUT_F + id]);
      dst[RANK + r] = 0;
    }
    #pragma unroll
    for (int r = 0; r < RANK; ++r)
      pdT[(size_t)r * IN_F + id] = f2bf(pd[(size_t)id * RANK + r]);
  }
}

// ---------------------------------------------------------------------------
// Kernel 2: lr partials = Aq @ pdT^T via MFMA (64 M-tiles x 4 K-chunks).
// ---------------------------------------------------------------------------
__global__ __launch_bounds__(256)
void lr_kernel(const ushort* __restrict__ A, const ushort* __restrict__ pdT,
               float* __restrict__ part)
{
  __shared__ alignas(16) ushort lA[64 * 64];
  const int tid  = threadIdx.x;
  const int wave = tid >> 6, lane = tid & 63;
  const int mt = blockIdx.x >> 2;
  const int kc = blockIdx.x & 3;
  const int k0 = kc * KCH;

  const int tr  = tid >> 3;
  const int scc = (tid & 7) ^ (tr & 7);
  const ushort* aSrc = A + (size_t)(mt * 64 + tr) * KTOT + k0 + scc * 8;
  char* ldsA = (char*)lA + wave * 1024;

  f32x4 acc[2];
  #pragma unroll
  for (int n = 0; n < 2; ++n) acc[n] = f32x4{0.f, 0.f, 0.f, 0.f};

  for (int kt = 0; kt < KCH / 64; ++kt) {
    const ushort* aS = aSrc + kt * 64;
    #pragma unroll
    for (int j = 0; j < 2; ++j)
      __builtin_amdgcn_global_load_lds(
          (const AS1 void*)(aS + (size_t)j * 32 * KTOT),
          (AS3 void*)(ldsA + j * 4096), 16, 0, 0);
    __syncthreads();
    #pragma unroll
    for (int ks = 0; ks < 2; ++ks) {
      const int kb  = (ks * 32 + (lane >> 4) * 8) * 2;
      const int row = wave * 16 + (lane & 15);
      const int addr = (row * 128 + kb) ^ ((row & 7) << 4);
      bf16x8 af = *(const bf16x8*)((const char*)lA + addr);
      #pragma unroll
      for (int n = 0; n < 2; ++n) {
        const int prow = n * 16 + (lane & 15);
        bf16x8 bf = *(const bf16x8*)(pdT + (size_t)prow * IN_F + k0 + kt * 64 + ks * 32 + (lane >> 4) * 8);
        acc[n] = __builtin_amdgcn_mfma_f32_16x16x32_bf16(af, bf, acc[n], 0, 0, 0);
      }
    }
    __syncthreads();
  }
  const int r0   = lane & 15;
  const int rowb = mt * 64 + wave * 16 + (lane >> 4) * 4;
  #pragma unroll
  for (int n = 0; n < 2; ++n)
    #pragma unroll
    for (int i = 0; i < 4; ++i)
      part[((size_t)kc * 4096 + rowb + i) * 32 + n * 16 + r0] = acc[n][i];
}

// ---------------------------------------------------------------------------
// Kernel 3: combine lr partials -> A_ext[:, 4096:4128], zero 4128:4160.
// ---------------------------------------------------------------------------
__global__ __launch_bounds__(256)
void lrcomb_kernel(const float* __restrict__ part, ushort* __restrict__ Aext)
{
  const int id  = blockIdx.x * 256 + threadIdx.x;
  const int row = id >> 5, r = id & 31;
  const float s = part[(size_t)row * 32 + r]
                + part[(size_t)(4096 + row) * 32 + r]
                + part[(size_t)(8192 + row) * 32 + r]
                + part[(size_t)(12288 + row) * 32 + r];
  ushort* dst = Aext + (size_t)row * KTOT + IN_F;
  dst[r]        = f2bf(s);
  dst[RANK + r] = 0;
}

// ---------------------------------------------------------------------------
// Kernel 4: 256x256 GEMM. R15 = R6 thin-phase 8-phase body (best measured at
// equal K: 128.4 @4224) at KTOT=4160 with buf0 tail. Minimal read ledger
// (12/4/8/0 per 4 phases, af held across MQ pair, b0 p1->p4, b1 p2->p3),
// DRAIN4 after phases 4/8, stage order B11,A11,A00,B00,B01,A01,A10,B10.
// Clamped t3 dup-stages touch only unread buf1-h0; final drain completes
// buf0-h1 so the tail (tile 64) reads buf0 only.
// ---------------------------------------------------------------------------
#define READ_AF8(DST, B_, MQ_)                                                   \
  { _Pragma("unroll")                                                            \
    for (int mf = 0; mf < 4; ++mf) {                                             \
      DST[mf][0] = *(const bf16x8*)(lds + afB0 + ((B_) * 32768 + (MQ_) * 8192 + mf * 2048)); \
      DST[mf][1] = *(const bf16x8*)(lds + afB1 + ((B_) * 32768 + (MQ_) * 8192 + mf * 2048)); \
    } }

#define READ_BF4(DST, B_, NQ_)                                                   \
  { _Pragma("unroll")                                                            \
    for (int nf = 0; nf < 2; ++nf) {                                             \
      DST[nf][0] = *(const bf16x8*)(lds + bfB0 + ((B_) * 32768 + (NQ_) * 4096 + nf * 2048)); \
      DST[nf][1] = *(const bf16x8*)(lds + bfB1 + ((B_) * 32768 + (NQ_) * 4096 + nf * 2048)); \
    } }

#define MFMA16(MQ_, NQ_, AF, BF)                                                 \
  _Pragma("unroll")                                                              \
  for (int mf = 0; mf < 4; ++mf)                                                 \
    _Pragma("unroll")                                                            \
    for (int nf = 0; nf < 2; ++nf)                                               \
      _Pragma("unroll")                                                          \
      for (int ks = 0; ks < 2; ++ks)                                             \
        acc[(MQ_) * 4 + mf][(NQ_) * 2 + nf] =                                    \
            __builtin_amdgcn_mfma_f32_16x16x32_bf16(AF[mf][ks], BF[nf][ks],      \
                acc[(MQ_) * 4 + mf][(NQ_) * 2 + nf], 0, 0, 0);

#define STAGE_A(B_, S0, S1, D0, D1, T_)                                          \
  { const ushort* s0 = Atile + S0 + (T_) * 64;                                   \
    const ushort* s1 = Atile + S1 + (T_) * 64;                                   \
    __builtin_amdgcn_global_load_lds((const AS1 void*)s0,                        \
        (AS3 void*)(lds + (B_) * 32768 + D0), 16, 0, 0);                         \
    __builtin_amdgcn_global_load_lds((const AS1 void*)s1,                        \
        (AS3 void*)(lds + (B_) * 32768 + D1), 16, 0, 0); }

#define STAGE_B(B_, S0, S1, D0, D1, T_)                                          \
  { const ushort* s0 = Btile + S0 + (T_) * 64;                                   \
    const ushort* s1 = Btile + S1 + (T_) * 64;                                   \
    __builtin_amdgcn_global_load_lds((const AS1 void*)s0,                        \
        (AS3 void*)(lds + 65536 + (B_) * 32768 + D0), 16, 0, 0);                 \
    __builtin_amdgcn_global_load_lds((const AS1 void*)s1,                        \
        (AS3 void*)(lds + 65536 + (B_) * 32768 + D1), 16, 0, 0); }

#define BAR __builtin_amdgcn_s_barrier()
#define DRAIN4 asm volatile("s_waitcnt vmcnt(4)" ::: "memory")
#define PRIO1 __builtin_amdgcn_s_setprio(1)
#define PRIO0 __builtin_amdgcn_s_setprio(0)

// Thin phase: [af reads if READA] + [BF reads if READB] + stage + BAR +
// 16 MFMA (setprio) + [DRAIN4] + BAR.
#define PHASE(B_, MQ_, NQ_, READA, READB, BF_, STAGE, W4)                        \
  {                                                                              \
    if (READA) READ_AF8(af, B_, MQ_);                                            \
    if (READB) READ_BF4(BF_, B_, NQ_);                                           \
    STAGE;                                                                       \
    BAR;                                                                         \
    PRIO1; MFMA16(MQ_, NQ_, af, BF_); PRIO0;                                     \
    if (W4) DRAIN4;                                                              \
    BAR;                                                                         \
  }

__global__ __launch_bounds__(512, 2)
void gemm256_kernel(const ushort* __restrict__ A, const ushort* __restrict__ B,
                    const float* __restrict__ bias, float* __restrict__ C)
{
  extern __shared__ char lds[];
  const int tid = threadIdx.x;
  const int w = tid >> 6, lane = tid & 63;
  const int l15 = lane & 15;
  const int wm = w >> 2, wn = w & 3;          // 2 x 4 waves

  // ds_read base vaddrs; imm offsets carry B_/MQ_/NQ_/frag (fit 16-bit).
  const int swz0 = (l15 * 128 + (lane >> 4) * 16) ^ ((l15 & 7) << 4);
  const int swz1 = (l15 * 128 + 64 + (lane >> 4) * 16) ^ ((l15 & 7) << 4);
  const int afB0 = wm * 16384 + swz0;
  const int afB1 = wm * 16384 + swz1;
  const int bfB0 = 65536 + wn * 8192 + swz0;
  const int bfB1 = 65536 + wn * 8192 + swz1;

  // Stage source offsets (ushort units) and LDS dest offsets (bytes).
  const int coff = ((lane & 7) ^ (lane >> 3)) << 3;
  const int g0 = w * 2, g1 = w * 2 + 1;
  const int aq0 = (g0 >> 3) * 2, asub0 = g0 & 7;
  const int aq1 = (g1 >> 3) * 2, asub1 = g1 & 7;
  const int aS00 = (aq0 * 64 + asub0 * 8 + (lane >> 3)) * KTOT + coff;
  const int aS01 = (aq1 * 64 + asub1 * 8 + (lane >> 3)) * KTOT + coff;
  const int aS10 = ((aq0 + 1) * 64 + asub0 * 8 + (lane >> 3)) * KTOT + coff;
  const int aS11 = ((aq1 + 1) * 64 + asub1 * 8 + (lane >> 3)) * KTOT + coff;
  const int aD00 = aq0 * 8192 + asub0 * 1024;
  const int aD01 = aq1 * 8192 + asub1 * 1024;
  const int aD10 = (aq0 + 1) * 8192 + asub0 * 1024;
  const int aD11 = (aq1 + 1) * 8192 + asub1 * 1024;
  const int bj0 = g0 >> 2, bsub0 = g0 & 3;
  const int bj1 = g1 >> 2, bsub1 = g1 & 3;
  const int bS00 = (bj0 * 64 + bsub0 * 8 + (lane >> 3)) * KTOT + coff;
  const int bS01 = (bj1 * 64 + bsub1 * 8 + (lane >> 3)) * KTOT + coff;
  const int bS10 = (bj0 * 64 + 32 + bsub0 * 8 + (lane >> 3)) * KTOT + coff;
  const int bS11 = (bj1 * 64 + 32 + bsub1 * 8 + (lane >> 3)) * KTOT + coff;
  const int bD00 = bj0 * 8192 + bsub0 * 1024;
  const int bD01 = bj1 * 8192 + bsub1 * 1024;
  const int bD10 = bj0 * 8192 + 4096 + bsub0 * 1024;
  const int bD11 = bj1 * 8192 + 4096 + bsub1 * 1024;

  // 2-D XCD chunk swizzle: each XCD owns a 4x8 (bm x bn) region.
  const int xcd = blockIdx.x & 7, idx = blockIdx.x >> 3;
  const int bm = (xcd >> 1) * 4 + (idx >> 3);
  const int bn = (xcd & 1) * 8 + (idx & 7);

  const ushort* Atile = A + (size_t)bm * 256 * KTOT;
  const ushort* Btile = B + (size_t)bn * 256 * KTOT;

  f32x4 acc[8][4];
  #pragma unroll
  for (int m = 0; m < 8; ++m)
    #pragma unroll
    for (int n = 0; n < 4; ++n)
      acc[m][n] = f32x4{0.f, 0.f, 0.f, 0.f};

  // Prologue: buf0 <- tile 0 full (8 loads); buf1 <- tile 1 h0 (4 loads).
  STAGE_A(0, aS00, aS01, aD00, aD01, 0);
  STAGE_B(0, bS00, bS01, bD00, bD01, 0);
  STAGE_A(0, aS10, aS11, aD10, aD11, 0);
  STAGE_B(0, bS10, bS11, bD10, bD11, 0);
  STAGE_A(1, aS00, aS01, aD00, aD01, 1);
  STAGE_B(1, bS00, bS01, bD00, bD01, 1);
  DRAIN4;           // buf0 complete; buf1-h0's 4 loads outstanding
  BAR;

  #pragma unroll 1
  for (int j = 0; j < ITERS; ++j) {
    const int t1 = 2 * j + 1;
    const int t2 = 2 * j + 2;                                  // <= 64, real
    const int t3 = (2 * j + 3 < NKT) ? 2 * j + 3 : NKT - 1;    // clamp (dup, unread)
    bf16x8 af[4][2], b0[2][2], b1[2][2];
    PHASE(0, 0, 0, 1, 1, b0, { STAGE_B(1, bS10, bS11, bD10, bD11, t1); }, 0)
    PHASE(0, 0, 1, 0, 1, b1, { STAGE_A(1, aS10, aS11, aD10, aD11, t1); }, 0)
    PHASE(0, 1, 1, 1, 0, b1, { STAGE_A(0, aS00, aS01, aD00, aD01, t2); }, 0)
    PHASE(0, 1, 0, 0, 0, b0, { STAGE_B(0, bS00, bS01, bD00, bD01, t2); }, 1)
    PHASE(1, 0, 0, 1, 1, b0, { STAGE_B(0, bS10, bS11, bD10, bD11, t2); }, 0)
    PHASE(1, 0, 1, 0, 1, b1, { STAGE_A(0, aS10, aS11, aD10, aD11, t2); }, 0)
    PHASE(1, 1, 1, 1, 0, b1, { STAGE_A(1, aS00, aS01, aD00, aD01, t3); }, 0)
    PHASE(1, 1, 0, 0, 0, b0, { STAGE_B(1, bS00, bS01, bD00, bD01, t3); }, 1)
  }

  // Tail: tile 64 fully resident in buf0 (staged j=31 phases 3-6; the final
  // DRAIN4 completed buf0-h1, leaving only the dup buf1-h0 stages in flight).
  {
    bf16x8 af[4][2], b0[2][2], b1[2][2];
    READ_AF8(af, 0, 0);
    READ_BF4(b0, 0, 0);
    READ_BF4(b1, 0, 1);
    MFMA16(0, 0, af, b0); MFMA16(0, 1, af, b1);
    READ_AF8(af, 0, 1);
    MFMA16(1, 0, af, b0); MFMA16(1, 1, af, b1);
  }

  // Epilogue: C = acc + bias. acc frag: col = l15, row = (lane>>4)*4 + i.
  const int csub = lane >> 4;
  #pragma unroll
  for (int nf = 0; nf < 4; ++nf) {
    const int col = bn * 256 + wn * 64 + nf * 16 + l15;
    const float bv = bias[col];
    #pragma unroll
    for (int mf = 0; mf < 8; ++mf) {
      const int row = bm * 256 + wm * 128 + mf * 16 + csub * 4;
      #pragma unroll
      for (int i = 0; i < 4; ++i)
        C[(size_t)(row + i) * OUT_F + col] = acc[mf][nf][i] + bv;
    }
  }
}

// ---------------------------------------------------------------------------
extern "C" void kernel_launch(void* const* d_in, const int* in_sizes, int n_in,
                              void* d_out, int out_size, void* d_ws, size_t ws_size,
                              hipStream_t stream) {
  const float* x    = (const float*)d_in[0];
  const int*   qw   = (const int*)d_in[1];
  const float* wsc  = (const float*)d_in[2];
  const float* bias = (const float*)d_in[3];
  const float* pd   = (const float*)d_in[4];
  const float* pu   = (const float*)d_in[5];
  float* out = (float*)d_out;

  ushort* Aext = (ushort*)d_ws;                        // [4096][4160] bf16
  ushort* Bext = Aext + (size_t)NTOK * KTOT;           // [4096][4160] bf16
  ushort* pdT  = Bext + (size_t)OUT_F * KTOT;          // [32][4096] bf16
  float*  part = (float*)(pdT + (size_t)RANK * IN_F);  // [4][4096][32] f32

  hipFuncSetAttribute(reinterpret_cast<const void*>(gemm256_kernel),
                      hipFuncAttributeMaxDynamicSharedMemorySize, 131072);

  prep_kernel  <<<24592, 256, 0, stream>>>(x, qw, wsc, pd, pu, Aext, Bext, pdT);
  lr_kernel    <<<  256, 256, 0, stream>>>(Aext, pdT, part);
  lrcomb_kernel<<<  512, 256, 0, stream>>>(part, Aext);
  gemm256_kernel<<< 256, 512, 131072, stream>>>(Aext, Bext, bias, out);
}